// Round 1
// baseline (1106.392 us; speedup 1.0000x reference)
//
#include <hip/hip_runtime.h>
#include <hip/hip_bf16.h>

#define HID 128
#define NRAW 127

// ---------------- CSR build ----------------

__global__ void count_deg_kernel(const int* __restrict__ dst, int* __restrict__ deg, int E) {
    int e = blockIdx.x * blockDim.x + threadIdx.x;
    if (e < E) atomicAdd(&deg[dst[e]], 1);
}

// blocks of 256 threads, 1024 elements each: local exclusive scan -> rp, block sum -> partials
__global__ void scanA_kernel(const int* __restrict__ deg, int* __restrict__ rp,
                             int* __restrict__ partials, int N) {
    __shared__ int sums[256];
    int t = threadIdx.x, b = blockIdx.x;
    int base = b * 1024;
    int v[4];
    int s = 0;
    #pragma unroll
    for (int j = 0; j < 4; ++j) {
        int i = base + t * 4 + j;
        v[j] = (i < N) ? deg[i] : 0;
        s += v[j];
    }
    sums[t] = s;
    __syncthreads();
    // Hillis-Steele inclusive scan over 256 thread sums
    for (int off = 1; off < 256; off <<= 1) {
        int add = (t >= off) ? sums[t - off] : 0;
        __syncthreads();
        sums[t] += add;
        __syncthreads();
    }
    int excl = sums[t] - s;  // exclusive prefix for this thread's 4 elements
    #pragma unroll
    for (int j = 0; j < 4; ++j) {
        int i = base + t * 4 + j;
        if (i < N) rp[i] = excl;
        excl += v[j];
    }
    if (t == 255) partials[b] = sums[255];
}

// single block scans nb (<=128) partials -> exclusive offsets
__global__ void scanB_kernel(const int* __restrict__ partials, int* __restrict__ offs, int nb) {
    __shared__ int sm[128];
    int t = threadIdx.x;
    int orig = (t < nb) ? partials[t] : 0;
    sm[t] = orig;
    __syncthreads();
    for (int off = 1; off < 128; off <<= 1) {
        int add = (t >= off) ? sm[t - off] : 0;
        __syncthreads();
        sm[t] += add;
        __syncthreads();
    }
    if (t < nb) offs[t] = sm[t] - orig;
}

__global__ void scanC_kernel(int* __restrict__ rp, int* __restrict__ cursor,
                             const int* __restrict__ offs, int N, int E) {
    int t = threadIdx.x, b = blockIdx.x;
    int o = offs[b];
    int base = b * 1024;
    #pragma unroll
    for (int j = 0; j < 4; ++j) {
        int i = base + t * 4 + j;
        if (i < N) {
            int v = rp[i] + o;
            rp[i] = v;
            cursor[i] = v;
        }
    }
    if (b == 0 && t == 0) rp[N] = E;
}

__global__ void scatter_kernel(const int* __restrict__ src, const int* __restrict__ dst,
                               int* __restrict__ cursor, int* __restrict__ csr, int E) {
    int e = blockIdx.x * blockDim.x + threadIdx.x;
    if (e < E) {
        int d = dst[e];
        int pos = atomicAdd(&cursor[d], 1);
        csr[pos] = src[e];
    }
}

// ---------------- h0 = concat(deg, feat) ----------------

__global__ void build_h0_kernel(const float* __restrict__ feat, const int* __restrict__ rp,
                                float* __restrict__ h0, int N) {
    int id = blockIdx.x * blockDim.x + threadIdx.x;
    if (id >= N * HID) return;
    int n = id >> 7, k = id & 127;
    float v;
    if (k == 0) v = (float)(rp[n + 1] - rp[n]);
    else        v = feat[n * NRAW + (k - 1)];
    h0[id] = v;
}

// ---------------- aggregation: one wave per node ----------------

__global__ __launch_bounds__(256) void agg_kernel(const float* __restrict__ h,
                                                  float* __restrict__ agg,
                                                  const int* __restrict__ rp,
                                                  const int* __restrict__ csr, int N) {
    int wave = threadIdx.x >> 6;
    int lane = threadIdx.x & 63;
    int i = blockIdx.x * 4 + wave;
    if (i >= N) return;
    int start = rp[i], end = rp[i + 1];
    const float2* h2 = (const float2*)h;
    float2 acc = make_float2(0.f, 0.f);
    int deg = end - start;
    if (deg == 0) {
        acc = h2[i * 64 + lane];
    } else {
        for (int e = start; e < end; e += 64) {
            int batch = min(end - e, 64);
            int mysrc = (lane < batch) ? csr[e + lane] : 0;
            int j0 = 0;
            for (; j0 + 8 <= batch; j0 += 8) {
                float2 v[8];
                #pragma unroll
                for (int j = 0; j < 8; ++j) {
                    int s = __shfl(mysrc, j0 + j);
                    v[j] = h2[s * 64 + lane];
                }
                #pragma unroll
                for (int j = 0; j < 8; ++j) { acc.x += v[j].x; acc.y += v[j].y; }
            }
            for (; j0 < batch; ++j0) {
                int s = __shfl(mysrc, j0);
                float2 v = h2[s * 64 + lane];
                acc.x += v.x; acc.y += v.y;
            }
        }
        float inv = 1.0f / (float)deg;
        acc.x *= inv; acc.y *= inv;
    }
    ((float2*)agg)[i * 64 + lane] = acc;
}

// ---------------- GEMM: out = relu(A @ W^T + b), A [N,128], W [128,128] ----------------

#define SA 132
#define SW 132

__global__ __launch_bounds__(256) void gemm_kernel(const float* __restrict__ A,
                                                   float* __restrict__ out,
                                                   const float* __restrict__ W,
                                                   const float* __restrict__ bias, int N) {
    __shared__ float Al[64 * SA];
    __shared__ float Wl[128 * SW];
    int t = threadIdx.x;
    int n0 = blockIdx.x * 64;

    // stage W (128x128 = 4096 float4)
    #pragma unroll
    for (int c = 0; c < 16; ++c) {
        int f = c * 256 + t;
        int o = f >> 5, k4 = f & 31;
        float4 v = ((const float4*)W)[f];
        *(float4*)&Wl[o * SW + k4 * 4] = v;
    }
    // stage A tile (64x128 = 2048 float4)
    #pragma unroll
    for (int c = 0; c < 8; ++c) {
        int f = c * 256 + t;
        int nl = f >> 5, k4 = f & 31;
        int n = n0 + nl;
        float4 v = (n < N) ? ((const float4*)A)[n * 32 + k4] : make_float4(0.f, 0.f, 0.f, 0.f);
        *(float4*)&Al[nl * SA + k4 * 4] = v;
    }
    __syncthreads();

    int tx = t & 15, ty = t >> 4;
    float acc[4][8];
    #pragma unroll
    for (int i = 0; i < 4; ++i)
        #pragma unroll
        for (int j = 0; j < 8; ++j) acc[i][j] = 0.f;

    for (int k4 = 0; k4 < 32; ++k4) {
        float4 a[4], w[8];
        #pragma unroll
        for (int i = 0; i < 4; ++i) a[i] = *(const float4*)&Al[(ty + 16 * i) * SA + k4 * 4];
        #pragma unroll
        for (int j = 0; j < 8; ++j) w[j] = *(const float4*)&Wl[(tx + 16 * j) * SW + k4 * 4];
        #pragma unroll
        for (int i = 0; i < 4; ++i)
            #pragma unroll
            for (int j = 0; j < 8; ++j) {
                acc[i][j] = fmaf(a[i].x, w[j].x, acc[i][j]);
                acc[i][j] = fmaf(a[i].y, w[j].y, acc[i][j]);
                acc[i][j] = fmaf(a[i].z, w[j].z, acc[i][j]);
                acc[i][j] = fmaf(a[i].w, w[j].w, acc[i][j]);
            }
    }

    #pragma unroll
    for (int j = 0; j < 8; ++j) {
        int o = tx + 16 * j;
        float b = bias[o];
        #pragma unroll
        for (int i = 0; i < 4; ++i) {
            int n = n0 + ty + 16 * i;
            if (n < N) {
                float v = acc[i][j] + b;
                out[n * HID + o] = fmaxf(v, 0.f);
            }
        }
    }
}

// ---------------- graph mean-pool ----------------

__global__ void pool_kernel(const float* __restrict__ h, const int* __restrict__ gid,
                            float* __restrict__ hg, int N) {
    int f = threadIdx.x & 127;
    int half = threadIdx.x >> 7;
    int n0 = blockIdx.x * 512;
    int nend = min(n0 + 512, N);
    float acc = 0.f;
    int cur = -1;
    for (int n = n0 + half; n < nend; n += 2) {
        int g = gid[n];
        if (g != cur) {
            if (cur >= 0) atomicAdd(&hg[cur * HID + f], acc);
            acc = 0.f;
            cur = g;
        }
        acc += h[n * HID + f];
    }
    if (cur >= 0) atomicAdd(&hg[cur * HID + f], acc);
}

__global__ void counts_kernel(const int* __restrict__ gid, float* __restrict__ counts, int N) {
    int t = blockIdx.x * blockDim.x + threadIdx.x;
    int n0 = t * 64;
    if (n0 >= N) return;
    int nend = min(n0 + 64, N);
    int cur = gid[n0];
    float c = 0.f;
    for (int n = n0; n < nend; ++n) {
        int g = gid[n];
        if (g != cur) { atomicAdd(&counts[cur], c); c = 0.f; cur = g; }
        c += 1.f;
    }
    atomicAdd(&counts[cur], c);
}

// ---------------- classifier head ----------------

// out[g][o] = (sum_k in[g][k]*W[o][k]) * inv + b[o]; inv = 1/max(counts[g],1) if counts else 1
__global__ void cls_kernel(const float* __restrict__ in, const float* __restrict__ W,
                           const float* __restrict__ b, float* __restrict__ out,
                           const float* __restrict__ counts, int G) {
    int id = blockIdx.x * blockDim.x + threadIdx.x;
    if (id >= G * HID) return;
    int g = id >> 7, o = id & 127;
    const float* row = in + g * HID;
    const float* w = W + o * HID;
    float s = 0.f;
    #pragma unroll 8
    for (int k = 0; k < HID; ++k) s = fmaf(row[k], w[k], s);
    float inv = 1.f;
    if (counts) inv = 1.f / fmaxf(counts[g], 1.f);
    out[id] = s * inv + b[o];
}

__global__ void cls3_kernel(const float* __restrict__ in, const float* __restrict__ W,
                            const float* __restrict__ b, float* __restrict__ out, int G) {
    int g = blockIdx.x * blockDim.x + threadIdx.x;
    if (g >= G) return;
    const float* row = in + g * HID;
    float s = 0.f;
    #pragma unroll 8
    for (int k = 0; k < HID; ++k) s = fmaf(row[k], W[k], s);
    out[g] = s + b[0];
}

// ---------------- launch ----------------

extern "C" void kernel_launch(void* const* d_in, const int* in_sizes, int n_in,
                              void* d_out, int out_size, void* d_ws, size_t ws_size,
                              hipStream_t stream) {
    const float* feat = (const float*)d_in[0];
    const int* src    = (const int*)d_in[1];
    const int* dst    = (const int*)d_in[2];
    const int* gid    = (const int*)d_in[3];
    // d_in[4] = num_graphs (device scalar) — use out_size instead
    const float* W0  = (const float*)d_in[5];
    const float* b0  = (const float*)d_in[6];
    const float* W1  = (const float*)d_in[7];
    const float* b1  = (const float*)d_in[8];
    const float* W2  = (const float*)d_in[9];
    const float* b2  = (const float*)d_in[10];
    const float* Wc1 = (const float*)d_in[11];
    const float* bc1 = (const float*)d_in[12];
    const float* Wc2 = (const float*)d_in[13];
    const float* bc2 = (const float*)d_in[14];

    const int N = in_sizes[3];
    const int E = in_sizes[1];
    const int G = out_size;

    // workspace layout
    char* ws = (char*)d_ws;
    size_t off = 0;
    auto alloc = [&](size_t bytes) { void* p = ws + off; off += (bytes + 255) & ~size_t(255); return p; };
    float* hA      = (float*)alloc((size_t)N * HID * 4);
    float* hB      = (float*)alloc((size_t)N * HID * 4);
    float* aggbuf  = (float*)alloc((size_t)N * HID * 4);
    int*   csr     = (int*)alloc((size_t)E * 4);
    int*   rp      = (int*)alloc((size_t)(N + 1) * 4);
    int*   cursor  = (int*)alloc((size_t)N * 4);
    int*   deg     = (int*)alloc((size_t)N * 4);
    int*   partials= (int*)alloc(256 * 4);
    int*   offs    = (int*)alloc(256 * 4);
    float* hg      = (float*)alloc((size_t)G * HID * 4);
    float* hg1     = (float*)alloc((size_t)G * HID * 4);
    float* hg2     = (float*)alloc((size_t)G * HID * 4);
    float* counts  = (float*)alloc((size_t)G * 4);

    hipMemsetAsync(deg, 0, (size_t)N * 4, stream);
    hipMemsetAsync(hg, 0, (size_t)G * HID * 4, stream);
    hipMemsetAsync(counts, 0, (size_t)G * 4, stream);

    int nb = (N + 1023) / 1024;

    count_deg_kernel<<<(E + 255) / 256, 256, 0, stream>>>(dst, deg, E);
    scanA_kernel<<<nb, 256, 0, stream>>>(deg, rp, partials, N);
    scanB_kernel<<<1, 128, 0, stream>>>(partials, offs, nb);
    scanC_kernel<<<nb, 256, 0, stream>>>(rp, cursor, offs, N, E);
    scatter_kernel<<<(E + 255) / 256, 256, 0, stream>>>(src, dst, cursor, csr, E);

    build_h0_kernel<<<(N * HID + 255) / 256, 256, 0, stream>>>(feat, rp, hA, N);

    int agg_grid = (N + 3) / 4;
    int gemm_grid = (N + 63) / 64;

    agg_kernel<<<agg_grid, 256, 0, stream>>>(hA, aggbuf, rp, csr, N);
    gemm_kernel<<<gemm_grid, 256, 0, stream>>>(aggbuf, hB, W0, b0, N);

    agg_kernel<<<agg_grid, 256, 0, stream>>>(hB, aggbuf, rp, csr, N);
    gemm_kernel<<<gemm_grid, 256, 0, stream>>>(aggbuf, hA, W1, b1, N);

    agg_kernel<<<agg_grid, 256, 0, stream>>>(hA, aggbuf, rp, csr, N);
    gemm_kernel<<<gemm_grid, 256, 0, stream>>>(aggbuf, hB, W2, b2, N);

    pool_kernel<<<(N + 511) / 512, 256, 0, stream>>>(hB, gid, hg, N);
    counts_kernel<<<(((N + 63) / 64) + 255) / 256, 256, 0, stream>>>(gid, counts, N);

    cls_kernel<<<(G * HID + 255) / 256, 256, 0, stream>>>(hg, Wc1, bc1, hg1, counts, G);
    cls_kernel<<<(G * HID + 255) / 256, 256, 0, stream>>>(hg1, Wc1, bc1, hg2, nullptr, G);
    cls3_kernel<<<1, 128, 0, stream>>>(hg2, Wc2, bc2, d_out ? (float*)d_out : nullptr, G);
}

// Round 2
// 517.311 us; speedup vs baseline: 2.1387x; 2.1387x over previous
//
#include <hip/hip_runtime.h>
#include <hip/hip_bf16.h>

#define HID 128
#define NRAW 127
#define BSH 8          // 256 nodes per bucket
#define BNODES 256
#define APAD 68        // LDS row pitch in u32 (16B-aligned, breaks pow2 stride)

typedef __attribute__((ext_vector_type(8))) short short8;
typedef __attribute__((ext_vector_type(4))) float floatx4;

__device__ inline unsigned pack_bf2(float x, float y) {
    unsigned bx = __float_as_uint(x);
    unsigned by = __float_as_uint(y);
    bx += 0x7fffu + ((bx >> 16) & 1u);   // RNE
    by += 0x7fffu + ((by >> 16) & 1u);
    return (bx >> 16) | (by & 0xffff0000u);
}
__device__ inline float bf_lo(unsigned u) { return __uint_as_float(u << 16); }
__device__ inline float bf_hi(unsigned u) { return __uint_as_float(u & 0xffff0000u); }

// ---------------- CSR build: bucketed 2-phase counting sort ----------------

__global__ __launch_bounds__(256) void bucket_count_kernel(const int* __restrict__ dst,
                                                           int* __restrict__ gbucket,
                                                           int E, int NB) {
    __shared__ int hist[512];
    int t = threadIdx.x;
    for (int b = t; b < NB; b += 256) hist[b] = 0;
    __syncthreads();
    int base = blockIdx.x * 4096;
    #pragma unroll
    for (int j = 0; j < 16; ++j) {
        int e = base + j * 256 + t;
        if (e < E) atomicAdd(&hist[dst[e] >> BSH], 1);
    }
    __syncthreads();
    for (int b = t; b < NB; b += 256) {
        int v = hist[b];
        if (v) atomicAdd(&gbucket[b], v);
    }
}

__global__ void bucket_scan_kernel(const int* __restrict__ gbucket, int* __restrict__ bstart,
                                   int* __restrict__ gcur, int NB, int E) {
    __shared__ int sm[512];
    int t = threadIdx.x;
    int v = (t < NB) ? gbucket[t] : 0;
    sm[t] = v;
    __syncthreads();
    for (int off = 1; off < 512; off <<= 1) {
        int add = (t >= off) ? sm[t - off] : 0;
        __syncthreads();
        sm[t] += add;
        __syncthreads();
    }
    if (t < NB) {
        int ex = sm[t] - v;
        bstart[t] = ex;
        gcur[t] = ex;
    }
    if (t == 0) bstart[NB] = E;
}

__global__ __launch_bounds__(256) void bucket_scatter_kernel(const int* __restrict__ src,
                                                             const int* __restrict__ dst,
                                                             int* __restrict__ gcur,
                                                             uint2* __restrict__ staging,
                                                             int E, int NB) {
    __shared__ int hist[512];
    __shared__ int base[512];
    int t = threadIdx.x;
    for (int b = t; b < NB; b += 256) hist[b] = 0;
    __syncthreads();
    int s[16], d[16], r[16];
    int e0 = blockIdx.x * 4096;
    #pragma unroll
    for (int j = 0; j < 16; ++j) {
        int e = e0 + j * 256 + t;
        if (e < E) {
            s[j] = src[e];
            d[j] = dst[e];
            r[j] = atomicAdd(&hist[d[j] >> BSH], 1);
        } else d[j] = -1;
    }
    __syncthreads();
    for (int b = t; b < NB; b += 256) {
        int v = hist[b];
        base[b] = v ? atomicAdd(&gcur[b], v) : 0;
    }
    __syncthreads();
    #pragma unroll
    for (int j = 0; j < 16; ++j) {
        if (d[j] >= 0) {
            int b = d[j] >> BSH;
            staging[base[b] + r[j]] = make_uint2((unsigned)s[j], (unsigned)d[j]);
        }
    }
}

__global__ __launch_bounds__(256) void csr_build_kernel(const uint2* __restrict__ staging,
                                                        const int* __restrict__ bstart,
                                                        int* __restrict__ rp, int* __restrict__ csr,
                                                        int N, int E, int NB) {
    __shared__ int hist[256];
    __shared__ int sm[256];
    __shared__ int excl[256];
    __shared__ int cnt[256];
    int t = threadIdx.x;
    int b = blockIdx.x;
    int nbase = b << BSH;
    int s0 = bstart[b], e1 = bstart[b + 1];
    hist[t] = 0;
    __syncthreads();
    for (int i = s0 + t; i < e1; i += 256) {
        uint2 p = staging[i];
        atomicAdd(&hist[p.y & (BNODES - 1)], 1);
    }
    __syncthreads();
    int h = hist[t];
    sm[t] = h;
    __syncthreads();
    for (int off = 1; off < 256; off <<= 1) {
        int add = (t >= off) ? sm[t - off] : 0;
        __syncthreads();
        sm[t] += add;
        __syncthreads();
    }
    excl[t] = sm[t] - h;
    cnt[t] = 0;
    int n = nbase + t;
    if (n < N) rp[n] = s0 + (sm[t] - h);
    if (b == NB - 1 && t == 0) rp[N] = E;
    __syncthreads();
    for (int i = s0 + t; i < e1; i += 256) {
        uint2 p = staging[i];
        int dl = p.y & (BNODES - 1);
        int pos = s0 + excl[dl] + atomicAdd(&cnt[dl], 1);
        csr[pos] = (int)p.x;
    }
}

// ---------------- weight fp32 -> bf16 pack ----------------

__global__ void wconv_kernel(const float* __restrict__ W0, const float* __restrict__ W1,
                             const float* __restrict__ W2,
                             unsigned* __restrict__ O0, unsigned* __restrict__ O1,
                             unsigned* __restrict__ O2) {
    int id = blockIdx.x * blockDim.x + threadIdx.x;
    if (id >= 3 * 8192) return;
    int sel = id >> 13, l = id & 8191;
    const float* W = sel == 0 ? W0 : (sel == 1 ? W1 : W2);
    unsigned* O = sel == 0 ? O0 : (sel == 1 ? O1 : O2);
    O[l] = pack_bf2(W[2 * l], W[2 * l + 1]);
}

// ---------------- h0 = concat(deg, feat) in bf16 ----------------

__global__ void build_h0_kernel(const float* __restrict__ feat, const int* __restrict__ rp,
                                unsigned* __restrict__ h0, int N) {
    int id = blockIdx.x * blockDim.x + threadIdx.x;
    if (id >= N * 64) return;
    int n = id >> 6, c = id & 63;
    const float* fr = feat + (size_t)n * NRAW;
    float x, y;
    if (c == 0) {
        x = (float)(rp[n + 1] - rp[n]);
        y = fr[0];
    } else {
        x = fr[2 * c - 1];
        y = fr[2 * c];
    }
    h0[id] = pack_bf2(x, y);
}

// ---------------- aggregation: one wave per node, bf16 gather ----------------

__global__ __launch_bounds__(256) void agg_kernel(const unsigned* __restrict__ h,
                                                  unsigned* __restrict__ agg,
                                                  const int* __restrict__ rp,
                                                  const int* __restrict__ csr, int N) {
    int wave = threadIdx.x >> 6, lane = threadIdx.x & 63;
    int i = blockIdx.x * 4 + wave;
    if (i >= N) return;
    int start = rp[i], end = rp[i + 1];
    int deg = end - start;
    if (deg == 0) {
        agg[i * 64 + lane] = h[i * 64 + lane];  // keep old h, exact
        return;
    }
    float ax = 0.f, ay = 0.f;
    for (int e = start; e < end; e += 64) {
        int batch = min(end - e, 64);
        int mysrc = (lane < batch) ? csr[e + lane] : 0;
        int j0 = 0;
        for (; j0 + 8 <= batch; j0 += 8) {
            unsigned v[8];
            #pragma unroll
            for (int j = 0; j < 8; ++j) {
                int sj = __shfl(mysrc, j0 + j);
                v[j] = h[sj * 64 + lane];
            }
            #pragma unroll
            for (int j = 0; j < 8; ++j) { ax += bf_lo(v[j]); ay += bf_hi(v[j]); }
        }
        for (; j0 < batch; ++j0) {
            int sj = __shfl(mysrc, j0);
            unsigned v = h[sj * 64 + lane];
            ax += bf_lo(v); ay += bf_hi(v);
        }
    }
    float inv = 1.f / (float)deg;
    agg[i * 64 + lane] = pack_bf2(ax * inv, ay * inv);
}

// ---------------- GEMM: out = relu(A @ W^T + b) via MFMA bf16 ----------------
// A [N,128] bf16, Wb [128,128] bf16 (row-major over k), out bf16.
// 16x16x32 layouts: A/B frag lane holds [idx = lane&15][k = (lane>>4)*8 + j];
// C/D: col = lane&15, row = (lane>>4)*4 + reg.

__global__ __launch_bounds__(256) void mfma_gemm_kernel(const unsigned* __restrict__ A,
                                                        unsigned* __restrict__ out,
                                                        const unsigned* __restrict__ Wb,
                                                        const float* __restrict__ bias, int N) {
    __shared__ unsigned Al[64 * APAD];
    __shared__ unsigned Wl[128 * APAD];
    int t = threadIdx.x;
    int n0 = blockIdx.x * 64;
    // stage W: 128 rows x 16 uint4
    #pragma unroll
    for (int c = 0; c < 8; ++c) {
        int f = c * 256 + t;
        int row = f >> 4, c4 = f & 15;
        uint4 v = ((const uint4*)Wb)[f];
        *(uint4*)&Wl[row * APAD + c4 * 4] = v;
    }
    // stage A: 64 rows x 16 uint4
    #pragma unroll
    for (int c = 0; c < 4; ++c) {
        int f = c * 256 + t;
        int row = f >> 4, c4 = f & 15;
        int n = n0 + row;
        uint4 v = make_uint4(0u, 0u, 0u, 0u);
        if (n < N) v = ((const uint4*)A)[n * 16 + c4];
        *(uint4*)&Al[row * APAD + c4 * 4] = v;
    }
    __syncthreads();

    int wv = t >> 6, lane = t & 63;
    int m = lane & 15, q = lane >> 4;
    floatx4 acc[8];
    #pragma unroll
    for (int ot = 0; ot < 8; ++ot) acc[ot] = (floatx4)(0.f);

    #pragma unroll
    for (int kt = 0; kt < 4; ++kt) {
        short8 af = *(const short8*)&Al[(wv * 16 + m) * APAD + kt * 16 + q * 4];
        #pragma unroll
        for (int ot = 0; ot < 8; ++ot) {
            short8 bf = *(const short8*)&Wl[(ot * 16 + m) * APAD + kt * 16 + q * 4];
            acc[ot] = __builtin_amdgcn_mfma_f32_16x16x32_bf16(af, bf, acc[ot], 0, 0, 0);
        }
    }

    unsigned short* oh = (unsigned short*)out;
    #pragma unroll
    for (int ot = 0; ot < 8; ++ot) {
        int o = ot * 16 + m;
        float bv = bias[o];
        #pragma unroll
        for (int r = 0; r < 4; ++r) {
            int n = n0 + wv * 16 + q * 4 + r;
            if (n < N) {
                float v = fmaxf(acc[ot][r] + bv, 0.f);
                unsigned bx = __float_as_uint(v);
                bx += 0x7fffu + ((bx >> 16) & 1u);
                oh[(size_t)n * 128 + o] = (unsigned short)(bx >> 16);
            }
        }
    }
}

// ---------------- graph mean-pool ----------------

__global__ void pool_kernel(const unsigned* __restrict__ h, const int* __restrict__ gid,
                            float* __restrict__ hg, int N) {
    int c = threadIdx.x & 63;
    int half = threadIdx.x >> 6;
    int n0 = blockIdx.x * 512;
    int nend = min(n0 + 512, N);
    float ax = 0.f, ay = 0.f;
    int cur = -1;
    for (int n = n0 + half; n < nend; n += 4) {
        int g = gid[n];
        if (g != cur) {
            if (cur >= 0) {
                atomicAdd(&hg[cur * HID + 2 * c], ax);
                atomicAdd(&hg[cur * HID + 2 * c + 1], ay);
            }
            ax = ay = 0.f;
            cur = g;
        }
        unsigned v = h[n * 64 + c];
        ax += bf_lo(v); ay += bf_hi(v);
    }
    if (cur >= 0) {
        atomicAdd(&hg[cur * HID + 2 * c], ax);
        atomicAdd(&hg[cur * HID + 2 * c + 1], ay);
    }
}

__global__ void counts_kernel(const int* __restrict__ gid, float* __restrict__ counts, int N) {
    int t = blockIdx.x * blockDim.x + threadIdx.x;
    int n0 = t * 64;
    if (n0 >= N) return;
    int nend = min(n0 + 64, N);
    int cur = gid[n0];
    float c = 0.f;
    for (int n = n0; n < nend; ++n) {
        int g = gid[n];
        if (g != cur) { atomicAdd(&counts[cur], c); c = 0.f; cur = g; }
        c += 1.f;
    }
    atomicAdd(&counts[cur], c);
}

// ---------------- classifier head (fp32) ----------------

__global__ void cls_kernel(const float* __restrict__ in, const float* __restrict__ W,
                           const float* __restrict__ b, float* __restrict__ out,
                           const float* __restrict__ counts, int G) {
    int id = blockIdx.x * blockDim.x + threadIdx.x;
    if (id >= G * HID) return;
    int g = id >> 7, o = id & 127;
    const float* row = in + g * HID;
    const float* w = W + o * HID;
    float s = 0.f;
    #pragma unroll 8
    for (int k = 0; k < HID; ++k) s = fmaf(row[k], w[k], s);
    float inv = 1.f;
    if (counts) inv = 1.f / fmaxf(counts[g], 1.f);
    out[id] = s * inv + b[o];
}

__global__ void cls3_kernel(const float* __restrict__ in, const float* __restrict__ W,
                            const float* __restrict__ b, float* __restrict__ out, int G) {
    int g = blockIdx.x * blockDim.x + threadIdx.x;
    if (g >= G) return;
    const float* row = in + g * HID;
    float s = 0.f;
    #pragma unroll 8
    for (int k = 0; k < HID; ++k) s = fmaf(row[k], W[k], s);
    out[g] = s + b[0];
}

// ---------------- launch ----------------

extern "C" void kernel_launch(void* const* d_in, const int* in_sizes, int n_in,
                              void* d_out, int out_size, void* d_ws, size_t ws_size,
                              hipStream_t stream) {
    const float* feat = (const float*)d_in[0];
    const int* src    = (const int*)d_in[1];
    const int* dst    = (const int*)d_in[2];
    const int* gid    = (const int*)d_in[3];
    const float* W0  = (const float*)d_in[5];
    const float* b0  = (const float*)d_in[6];
    const float* W1  = (const float*)d_in[7];
    const float* b1  = (const float*)d_in[8];
    const float* W2  = (const float*)d_in[9];
    const float* b2  = (const float*)d_in[10];
    const float* Wc1 = (const float*)d_in[11];
    const float* bc1 = (const float*)d_in[12];
    const float* Wc2 = (const float*)d_in[13];
    const float* bc2 = (const float*)d_in[14];

    const int N = in_sizes[3];
    const int E = in_sizes[1];
    const int G = out_size;
    const int NB = (N + BNODES - 1) >> BSH;   // 391 for N=100000 (must be <= 512)

    char* ws = (char*)d_ws;
    size_t off = 0;
    auto alloc = [&](size_t bytes) { void* p = ws + off; off += (bytes + 255) & ~size_t(255); return p; };
    unsigned* hA     = (unsigned*)alloc((size_t)N * 64 * 4);
    unsigned* hB     = (unsigned*)alloc((size_t)N * 64 * 4);
    unsigned* aggbuf = (unsigned*)alloc((size_t)N * 64 * 4);
    uint2* staging   = (uint2*)alloc((size_t)E * 8);
    int* csr         = (int*)alloc((size_t)E * 4);
    int* rp          = (int*)alloc((size_t)(N + 1) * 4);
    int* gbucket     = (int*)alloc(512 * 4);
    int* bstart      = (int*)alloc(513 * 4);
    int* gcur        = (int*)alloc(512 * 4);
    unsigned* Wb0    = (unsigned*)alloc(8192 * 4);
    unsigned* Wb1    = (unsigned*)alloc(8192 * 4);
    unsigned* Wb2    = (unsigned*)alloc(8192 * 4);
    float* hg        = (float*)alloc((size_t)G * HID * 4);
    float* hg1      = (float*)alloc((size_t)G * HID * 4);
    float* hg2      = (float*)alloc((size_t)G * HID * 4);
    float* counts   = (float*)alloc((size_t)G * 4);

    hipMemsetAsync(gbucket, 0, 512 * 4, stream);
    hipMemsetAsync(hg, 0, (size_t)G * HID * 4, stream);
    hipMemsetAsync(counts, 0, (size_t)G * 4, stream);

    int gE = (E + 4095) / 4096;
    bucket_count_kernel<<<gE, 256, 0, stream>>>(dst, gbucket, E, NB);
    bucket_scan_kernel<<<1, 512, 0, stream>>>(gbucket, bstart, gcur, NB, E);
    bucket_scatter_kernel<<<gE, 256, 0, stream>>>(src, dst, gcur, staging, E, NB);
    csr_build_kernel<<<NB, 256, 0, stream>>>(staging, bstart, rp, csr, N, E, NB);

    wconv_kernel<<<(3 * 8192 + 255) / 256, 256, 0, stream>>>(W0, W1, W2, Wb0, Wb1, Wb2);
    build_h0_kernel<<<(N * 64 + 255) / 256, 256, 0, stream>>>(feat, rp, hA, N);

    int agg_grid = (N + 3) / 4;
    int gemm_grid = (N + 63) / 64;

    agg_kernel<<<agg_grid, 256, 0, stream>>>(hA, aggbuf, rp, csr, N);
    mfma_gemm_kernel<<<gemm_grid, 256, 0, stream>>>(aggbuf, hB, Wb0, b0, N);

    agg_kernel<<<agg_grid, 256, 0, stream>>>(hB, aggbuf, rp, csr, N);
    mfma_gemm_kernel<<<gemm_grid, 256, 0, stream>>>(aggbuf, hA, Wb1, b1, N);

    agg_kernel<<<agg_grid, 256, 0, stream>>>(hA, aggbuf, rp, csr, N);
    mfma_gemm_kernel<<<gemm_grid, 256, 0, stream>>>(aggbuf, hB, Wb2, b2, N);

    pool_kernel<<<(N + 511) / 512, 256, 0, stream>>>(hB, gid, hg, N);
    counts_kernel<<<(((N + 63) / 64) + 255) / 256, 256, 0, stream>>>(gid, counts, N);

    cls_kernel<<<(G * HID + 255) / 256, 256, 0, stream>>>(hg, Wc1, bc1, hg1, counts, G);
    cls_kernel<<<(G * HID + 255) / 256, 256, 0, stream>>>(hg1, Wc1, bc1, hg2, nullptr, G);
    cls3_kernel<<<1, 128, 0, stream>>>(hg2, Wc2, bc2, (float*)d_out, G);
}